// Round 7
// baseline (359.686 us; speedup 1.0000x reference)
//
#include <hip/hip_runtime.h>
#include <math.h>

// Mixture-of-logistics mean log-prob.
// log_prob(b,t) = lse_k(w + comp) - lse_k(w),  comp = -|z| - 2*log1p(e^-|z|) - log(s)
// with z = (x - loc)/s.  -log(s) is folded in as *rcp(s) after the exp.
// 4 lanes per row (each owns one float4 K-chunk) -> fully coalesced wave loads.

__global__ __launch_bounds__(256) void mol_main(
    const float* __restrict__ w,
    const float* __restrict__ loc,
    const float* __restrict__ sc,
    const float* __restrict__ tgt,
    float* __restrict__ partial, int nrows)
{
    const int tid      = blockIdx.x * blockDim.x + threadIdx.x;
    const int nthreads = gridDim.x * blockDim.x;
    const int c        = tid & 3;           // K-chunk index (0..3), 4 floats each
    float acc = 0.f;

    for (int row = (tid >> 2); row < nrows; row += (nthreads >> 2)) {
        const size_t base = (size_t)row * 16 + (size_t)c * 4;
        const float4 w4 = *(const float4*)(w   + base);
        const float4 l4 = *(const float4*)(loc + base);
        const float4 s4 = *(const float4*)(sc  + base);
        const float  x  = tgt[row];         // 4 lanes broadcast same addr

        float wv[4] = {w4.x, w4.y, w4.z, w4.w};
        float lv[4] = {l4.x, l4.y, l4.z, l4.w};
        float sv[4] = {s4.x, s4.y, s4.z, s4.w};
        float av[4], rv[4];
        #pragma unroll
        for (int j = 0; j < 4; ++j) {
            const float r  = __builtin_amdgcn_rcpf(sv[j]);   // 1/scale, ~1 ulp
            const float z  = (x - lv[j]) * r;
            const float az = fabsf(z);
            const float e  = __expf(-az);                    // underflows to 0 safely
            av[j] = wv[j] - az - 2.f * __logf(1.f + e);      // w + comp + log(s)  (a')
            rv[j] = r;
        }

        // max over the 16 mixture components (4 per lane x 4 lanes)
        float mw = fmaxf(fmaxf(wv[0], wv[1]), fmaxf(wv[2], wv[3]));
        float ma = fmaxf(fmaxf(av[0], av[1]), fmaxf(av[2], av[3]));
        mw = fmaxf(mw, __shfl_xor(mw, 1));
        mw = fmaxf(mw, __shfl_xor(mw, 2));
        ma = fmaxf(ma, __shfl_xor(ma, 1));
        ma = fmaxf(ma, __shfl_xor(ma, 2));

        float sw = 0.f, sa = 0.f;
        #pragma unroll
        for (int j = 0; j < 4; ++j) {
            sw += __expf(wv[j] - mw);
            sa += __expf(av[j] - ma) * rv[j];   // * (1/s) == exp(a' - log s - ma)
        }
        sw += __shfl_xor(sw, 1); sw += __shfl_xor(sw, 2);
        sa += __shfl_xor(sa, 1); sa += __shfl_xor(sa, 2);

        if (c == 0)
            acc += (ma + __logf(sa)) - (mw + __logf(sw));
    }

    // block reduce (wave64 shuffle, then LDS across the 4 waves)
    #pragma unroll
    for (int off = 32; off > 0; off >>= 1) acc += __shfl_down(acc, off);
    __shared__ float smem[4];
    const int lane = threadIdx.x & 63, wid = threadIdx.x >> 6;
    if (lane == 0) smem[wid] = acc;
    __syncthreads();
    if (threadIdx.x == 0)
        partial[blockIdx.x] = smem[0] + smem[1] + smem[2] + smem[3];
}

__global__ __launch_bounds__(256) void mol_final(
    const float* __restrict__ partial, int n,
    float* __restrict__ out, float inv_count)
{
    double acc = 0.0;
    for (int i = threadIdx.x; i < n; i += 256) acc += (double)partial[i];
    #pragma unroll
    for (int off = 32; off > 0; off >>= 1) acc += __shfl_down(acc, off);
    __shared__ double smem[4];
    const int lane = threadIdx.x & 63, wid = threadIdx.x >> 6;
    if (lane == 0) smem[wid] = acc;
    __syncthreads();
    if (threadIdx.x == 0)
        out[0] = (float)((smem[0] + smem[1] + smem[2] + smem[3]) * (double)inv_count);
}

extern "C" void kernel_launch(void* const* d_in, const int* in_sizes, int n_in,
                              void* d_out, int out_size, void* d_ws, size_t ws_size,
                              hipStream_t stream) {
    const float* w   = (const float*)d_in[0];
    const float* loc = (const float*)d_in[1];
    const float* sc  = (const float*)d_in[2];
    const float* tgt = (const float*)d_in[3];
    float* out     = (float*)d_out;
    float* partial = (float*)d_ws;          // overwritten fully each call
    const int nrows = in_sizes[3];          // B*T = 2,097,152

    int blocks = 2048;                      // grid-stride; ~8 blocks/CU worth of waves
    if (ws_size < (size_t)blocks * sizeof(float))
        blocks = (int)(ws_size / sizeof(float));

    mol_main<<<blocks, 256, 0, stream>>>(w, loc, sc, tgt, partial, nrows);
    mol_final<<<1, 256, 0, stream>>>(partial, blocks, out, 1.0f / (float)nrows);
}